// Round 1
// baseline (1119.919 us; speedup 1.0000x reference)
//
#include <hip/hip_runtime.h>
#include <cstdint>

typedef unsigned short u16;
typedef unsigned int   u32;
typedef u16    u16x4  __attribute__((ext_vector_type(4)));
typedef u16    u16x8  __attribute__((ext_vector_type(8)));
typedef __bf16 bf16x8 __attribute__((ext_vector_type(8)));
typedef float  f32x4  __attribute__((ext_vector_type(4)));

__device__ __forceinline__ u16 f2b(float x) {
  u32 u = __builtin_bit_cast(u32, x);
  u32 r = (u + 0x7fffu + ((u >> 16) & 1u)) >> 16;
  return (u16)r;
}
__device__ __forceinline__ float b2f(u16 u) {
  return __builtin_bit_cast(float, (u32)u << 16);
}

// async global->LDS, 16B per lane. LDS dest must be wave-uniform base + lane*16.
__device__ __forceinline__ void gl2lds16(const u16* g, u16* l) {
  __builtin_amdgcn_global_load_lds(
      (__attribute__((address_space(1))) void*)g,
      (__attribute__((address_space(3))) void*)l, 16, 0, 0);
}

// ---------------------------------------------------------------------------
// f32 -> bf16 elementwise conversion (n divisible by 4)
// ---------------------------------------------------------------------------
__global__ __launch_bounds__(256) void cvt_f32_bf16(
    const float* __restrict__ in, u16* __restrict__ out, long n)
{
  long i = ((long)blockIdx.x * 256 + threadIdx.x) * 4;
  if (i >= n) return;
  f32x4 v = *(const f32x4*)&in[i];
  u16x4 o = { f2b(v[0]), f2b(v[1]), f2b(v[2]), f2b(v[3]) };
  *(u16x4*)&out[i] = o;
}

// ---------------------------------------------------------------------------
// C[m,n] = A[m,:] . B[n,:] + bias[n]  (optional relu), bf16 in/out, f32 acc.
// A: [M,K] bf16 row-major, B: [N,K] bf16 row-major (i.e. B^T of math B).
// 128x128 tile, BK=32, 256 threads = 4 waves in 2x2, each wave 64x64 (4x4 MFMA).
// ---------------------------------------------------------------------------
#define BM 128
#define BN 128
#define BKK 32

__global__ __launch_bounds__(256) void gemm_bt(
    const u16* __restrict__ A, const u16* __restrict__ B,
    const float* __restrict__ bias, u16* __restrict__ C,
    int M, int N, int K, int relu)
{
  __shared__ __attribute__((aligned(16))) u16 As[BM * BKK];
  __shared__ __attribute__((aligned(16))) u16 Bs[BN * BKK];

  const int tid  = threadIdx.x;
  const int lane = tid & 63;
  const int wave = tid >> 6;
  const int lr   = lane & 15;   // M/N index within 16-tile
  const int quad = lane >> 4;   // k quad: k = quad*8 + j
  const int wm = (wave >> 1) * 64;
  const int wn = (wave & 1) * 64;

  const long m0 = (long)blockIdx.y * BM;
  const long n0 = (long)blockIdx.x * BN;

  // staging: 512 chunks of 16B (8 bf16) per tile; thread t does chunks t, t+256
  const int c1  = tid + 256;
  const int ar0 = tid >> 2, ac0 = (tid & 3) * 8;
  const int ar1 = c1 >> 2,  ac1 = (c1 & 3) * 8;

  const u16* Ab = A + m0 * K;
  const u16* Bb = B + n0 * K;

  f32x4 acc[4][4] = {};

  for (int k0 = 0; k0 < K; k0 += BKK) {
    __syncthreads();
    gl2lds16(Ab + (long)ar0 * K + (k0 + ac0), &As[tid * 8]);
    gl2lds16(Ab + (long)ar1 * K + (k0 + ac1), &As[c1 * 8]);
    gl2lds16(Bb + (long)ar0 * K + (k0 + ac0), &Bs[tid * 8]);
    gl2lds16(Bb + (long)ar1 * K + (k0 + ac1), &Bs[c1 * 8]);
    __syncthreads();

    bf16x8 af[4], bff[4];
#pragma unroll
    for (int i = 0; i < 4; ++i)
      af[i] = *(const bf16x8*)&As[(wm + i * 16 + lr) * BKK + quad * 8];
#pragma unroll
    for (int i = 0; i < 4; ++i)
      bff[i] = *(const bf16x8*)&Bs[(wn + i * 16 + lr) * BKK + quad * 8];
#pragma unroll
    for (int i = 0; i < 4; ++i)
#pragma unroll
      for (int j = 0; j < 4; ++j)
        acc[i][j] = __builtin_amdgcn_mfma_f32_16x16x32_bf16(af[i], bff[j], acc[i][j], 0, 0, 0);
  }

  // C/D layout: col = lane&15, row = quad*4 + reg
#pragma unroll
  for (int j = 0; j < 4; ++j) {
    const int col = wn + j * 16 + lr;
    const float bv = bias[n0 + col];
#pragma unroll
    for (int i = 0; i < 4; ++i) {
#pragma unroll
      for (int r = 0; r < 4; ++r) {
        const int row = wm + i * 16 + quad * 4 + r;
        float v = acc[i][j][r] + bv;
        if (relu) v = fmaxf(v, 0.0f);
        C[(m0 + row) * (long)N + (n0 + col)] = f2b(v);
      }
    }
  }
}

// ---------------------------------------------------------------------------
// Attention per (b,a): 1024 blocks, 256 threads.
//  q tile: Qp contiguous [h=256][l=128] at row 32a
//  k/v pre: Kp/Vp contiguous [h=256][kk=64] at row 16a
//  k[h][r] = sum_kk kpre[h][kk]*fac[a][kk][r] (k scaled by 1/16)
//  scores[l][r] = sum_h q[h][l]*k[h][r]; softmax over r (16); 
//  ctx[l][h] = sum_r attn[l][r]*v[h][r], written contiguous [l][h]
// ---------------------------------------------------------------------------
__global__ __launch_bounds__(256) void attn_kernel(
    const u16* __restrict__ Qp, const u16* __restrict__ Kp,
    const u16* __restrict__ Vp, const float* __restrict__ factor,
    u16* __restrict__ Ctx)
{
  __shared__ __attribute__((aligned(16))) float fac_s[64 * 16];
  __shared__ __attribute__((aligned(16))) float k_s[256][20];
  __shared__ __attribute__((aligned(16))) float v_s[256][20];
  __shared__ __attribute__((aligned(16))) float s_s[128][20];

  const int t = threadIdx.x;
  const int b = blockIdx.x >> 6;
  const int a = blockIdx.x & 63;

  for (int i = t; i < 1024; i += 256) fac_s[i] = factor[a * 1024 + i];
  __syncthreads();

  // phase 1: k_s / v_s, thread t <-> h = t
  {
    const long kb = (((long)(b * 1024 + a * 16)) << 10) + (long)t * 64;
    float kacc[16] = {}, vacc[16] = {};
    for (int kk8 = 0; kk8 < 64; kk8 += 8) {
      u16x8 kv8 = *(const u16x8*)&Kp[kb + kk8];
      u16x8 vv8 = *(const u16x8*)&Vp[kb + kk8];
#pragma unroll
      for (int j = 0; j < 8; ++j) {
        const float kv = b2f(kv8[j]), vv = b2f(vv8[j]);
        const float* fr = &fac_s[(kk8 + j) * 16];
#pragma unroll
        for (int r = 0; r < 16; ++r) { kacc[r] += kv * fr[r]; vacc[r] += vv * fr[r]; }
      }
    }
#pragma unroll
    for (int r = 0; r < 16; ++r) { k_s[t][r] = kacc[r] * 0.0625f; v_s[t][r] = vacc[r]; }
  }
  __syncthreads();

  // phase 2: scores; thread t <-> (l = t&127, half = t>>7 covering 8 r's)
  {
    const int l = t & 127, half = t >> 7;
    const long qb = (((long)(b * 2048 + a * 32)) << 10) + l;
    f32x4 acc0 = {}, acc1 = {};
    for (int h = 0; h < 256; ++h) {
      const float qv = b2f(Qp[qb + (long)h * 128]);
      f32x4 k0 = *(const f32x4*)&k_s[h][half * 8];
      f32x4 k1 = *(const f32x4*)&k_s[h][half * 8 + 4];
      acc0 += k0 * qv;
      acc1 += k1 * qv;
    }
    *(f32x4*)&s_s[l][half * 8]     = acc0;
    *(f32x4*)&s_s[l][half * 8 + 4] = acc1;
  }
  __syncthreads();

  // phase 3: softmax over r, threads 0..127
  if (t < 128) {
    float vals[16];
    float m = -1e30f;
#pragma unroll
    for (int r = 0; r < 16; ++r) { vals[r] = s_s[t][r]; m = fmaxf(m, vals[r]); }
    float sum = 0.0f;
#pragma unroll
    for (int r = 0; r < 16; ++r) { vals[r] = __expf(vals[r] - m); sum += vals[r]; }
    const float inv = 1.0f / sum;
#pragma unroll
    for (int r = 0; r < 16; ++r) s_s[t][r] = vals[r] * inv;
  }
  __syncthreads();

  // phase 4: ctx[l][h], thread t <-> h = t
  {
    f32x4 v0 = *(const f32x4*)&v_s[t][0];
    f32x4 v1 = *(const f32x4*)&v_s[t][4];
    f32x4 v2 = *(const f32x4*)&v_s[t][8];
    f32x4 v3 = *(const f32x4*)&v_s[t][12];
    const long cb = (((long)(b * 2048 + a * 32)) << 10) + t;
    for (int l = 0; l < 128; ++l) {
      f32x4 a0 = *(const f32x4*)&s_s[l][0];
      f32x4 a1 = *(const f32x4*)&s_s[l][4];
      f32x4 a2 = *(const f32x4*)&s_s[l][8];
      f32x4 a3 = *(const f32x4*)&s_s[l][12];
      f32x4 p = a0 * v0 + a1 * v1 + a2 * v2 + a3 * v3;
      Ctx[cb + (long)l * 256] = f2b(p[0] + p[1] + p[2] + p[3]);
    }
  }
}

// ---------------------------------------------------------------------------
// Residual + LayerNorm: one block (256 thr) per row of 1024.
// x = bf16(Y) + Q(f32); out = (x-mu)*rsqrt(var+eps)*gamma + beta
// ---------------------------------------------------------------------------
__global__ __launch_bounds__(256) void ln_kernel(
    const u16* __restrict__ Y, const float* __restrict__ Qin,
    const float* __restrict__ gamma, const float* __restrict__ beta,
    float* __restrict__ out)
{
  const long row = blockIdx.x;
  const int t = threadIdx.x;
  const long base = (row << 10) + (long)t * 4;

  u16x4 y4 = *(const u16x4*)&Y[base];
  f32x4 q4 = *(const f32x4*)&Qin[base];
  f32x4 x;
#pragma unroll
  for (int c = 0; c < 4; ++c) x[c] = b2f(y4[c]) + q4[c];

  float s  = x[0] + x[1] + x[2] + x[3];
  float sq = x[0]*x[0] + x[1]*x[1] + x[2]*x[2] + x[3]*x[3];
#pragma unroll
  for (int o = 1; o < 64; o <<= 1) {
    s  += __shfl_xor(s, o);
    sq += __shfl_xor(sq, o);
  }
  __shared__ float red[8];
  if ((t & 63) == 0) { red[(t >> 6) * 2] = s; red[(t >> 6) * 2 + 1] = sq; }
  __syncthreads();
  s  = red[0] + red[2] + red[4] + red[6];
  sq = red[1] + red[3] + red[5] + red[7];

  const float mean = s * (1.0f / 1024.0f);
  const float var  = sq * (1.0f / 1024.0f) - mean * mean;
  const float rstd = rsqrtf(var + 1e-5f);

  f32x4 g4 = *(const f32x4*)&gamma[t * 4];
  f32x4 be4 = *(const f32x4*)&beta[t * 4];
  f32x4 o4;
#pragma unroll
  for (int c = 0; c < 4; ++c) o4[c] = (x[c] - mean) * rstd * g4[c] + be4[c];
  *(f32x4*)&out[base] = o4;
}

// ---------------------------------------------------------------------------
extern "C" void kernel_launch(void* const* d_in, const int* in_sizes, int n_in,
                              void* d_out, int out_size, void* d_ws, size_t ws_size,
                              hipStream_t stream)
{
  (void)in_sizes; (void)n_in; (void)out_size; (void)ws_size;
  const float* Q      = (const float*)d_in[0];
  const float* K      = (const float*)d_in[1];
  const float* V      = (const float*)d_in[2];
  const float* WQ     = (const float*)d_in[3];
  const float* bQ     = (const float*)d_in[4];
  const float* WK     = (const float*)d_in[5];
  const float* bK     = (const float*)d_in[6];
  const float* WV     = (const float*)d_in[7];
  const float* bV     = (const float*)d_in[8];
  const float* factor = (const float*)d_in[9];
  const float* W1     = (const float*)d_in[10];
  const float* b1     = (const float*)d_in[11];
  const float* W2     = (const float*)d_in[12];
  const float* b2     = (const float*)d_in[13];
  const float* gamma  = (const float*)d_in[14];
  const float* beta   = (const float*)d_in[15];
  float* out = (float*)d_out;

  const long NQ = 33554432L;  // 16*2048*1024
  const long NK = 16777216L;  // 16*1024*1024
  const long ND = 1048576L;   // 1024*1024
  const long NW = 2097152L;   // 2048*1024

  char* w = (char*)d_ws;
  u16* Qb  = (u16*)(w);                    // 64 MB  [0, 64M)
  u16* Kb  = (u16*)(w + 67108864L);        // 32 MB
  u16* Vb  = (u16*)(w + 100663296L);       // 32 MB
  u16* WQb = (u16*)(w + 134217728L);       // 2 MB
  u16* WKb = (u16*)(w + 136314880L);       // 2 MB
  u16* WVb = (u16*)(w + 138412032L);       // 2 MB
  u16* W1b = (u16*)(w + 140509184L);       // 4 MB
  u16* W2b = (u16*)(w + 144703488L);       // 4 MB
  u16* Qp  = (u16*)(w + 148897792L);       // 64 MB
  u16* Kp  = (u16*)(w + 216006656L);       // 32 MB
  u16* Vp  = (u16*)(w + 249561088L);       // 32 MB
  u16* Ctx = (u16*)(w + 283115520L);       // 64 MB  -> peak 350,224,384 B
  u16* Hb  = (u16*)(w);                    // reuse Qb/Kb/Vb region (128 MB)
  u16* Yb  = (u16*)(w + 216006656L);       // reuse Kp/Vp region (64 MB)

  // convert inputs/weights to bf16
  cvt_f32_bf16<<<(int)(NQ / 1024), 256, 0, stream>>>(Q,  Qb,  NQ);
  cvt_f32_bf16<<<(int)(NK / 1024), 256, 0, stream>>>(K,  Kb,  NK);
  cvt_f32_bf16<<<(int)(NK / 1024), 256, 0, stream>>>(V,  Vb,  NK);
  cvt_f32_bf16<<<(int)(ND / 1024), 256, 0, stream>>>(WQ, WQb, ND);
  cvt_f32_bf16<<<(int)(ND / 1024), 256, 0, stream>>>(WK, WKb, ND);
  cvt_f32_bf16<<<(int)(ND / 1024), 256, 0, stream>>>(WV, WVb, ND);
  cvt_f32_bf16<<<(int)(NW / 1024), 256, 0, stream>>>(W1, W1b, NW);
  cvt_f32_bf16<<<(int)(NW / 1024), 256, 0, stream>>>(W2, W2b, NW);

  // projections
  gemm_bt<<<dim3(8, 256),  256, 0, stream>>>(Qb, WQb, bQ, Qp, 32768, 1024, 1024, 0);
  gemm_bt<<<dim3(8, 128),  256, 0, stream>>>(Kb, WKb, bK, Kp, 16384, 1024, 1024, 0);
  gemm_bt<<<dim3(8, 128),  256, 0, stream>>>(Vb, WVb, bV, Vp, 16384, 1024, 1024, 0);

  // low-rank attention
  attn_kernel<<<1024, 256, 0, stream>>>(Qp, Kp, Vp, factor, Ctx);

  // FFN
  gemm_bt<<<dim3(16, 256), 256, 0, stream>>>(Ctx, W1b, b1, Hb, 32768, 2048, 1024, 1);
  gemm_bt<<<dim3(8, 256),  256, 0, stream>>>(Hb, W2b, b2, Yb, 32768, 1024, 2048, 0);

  // residual + layernorm
  ln_kernel<<<32768, 256, 0, stream>>>(Yb, Q, gamma, beta, out);
}

// Round 2
// 1057.251 us; speedup vs baseline: 1.0593x; 1.0593x over previous
//
#include <hip/hip_runtime.h>
#include <cstdint>

typedef unsigned short u16;
typedef unsigned int   u32;
typedef u16    u16x4  __attribute__((ext_vector_type(4)));
typedef u16    u16x8  __attribute__((ext_vector_type(8)));
typedef __bf16 bf16x8 __attribute__((ext_vector_type(8)));
typedef float  f32x4  __attribute__((ext_vector_type(4)));

__device__ __forceinline__ u16 f2b(float x) {
  u32 u = __builtin_bit_cast(u32, x);
  u32 r = (u + 0x7fffu + ((u >> 16) & 1u)) >> 16;
  return (u16)r;
}
__device__ __forceinline__ float b2f(u16 u) {
  return __builtin_bit_cast(float, (u32)u << 16);
}

// async global->LDS, 16B per lane. LDS dest must be wave-uniform base + lane*16.
__device__ __forceinline__ void gl2lds16(const u16* g, u16* l) {
  __builtin_amdgcn_global_load_lds(
      (__attribute__((address_space(1))) void*)g,
      (__attribute__((address_space(3))) void*)l, 16, 0, 0);
}

// ---------------------------------------------------------------------------
// One fused f32 -> bf16 conversion over 8 concatenated segments.
// All segment sizes are multiples of 1024; each block handles 1024 elements.
// ---------------------------------------------------------------------------
struct CvtArgs {
  const float* src[8];
  u16*         dst[8];
  long         end[8];   // cumulative element counts
};

__global__ __launch_bounds__(256) void cvt_all(CvtArgs a)
{
  long g = (long)blockIdx.x * 1024;
  int seg = 0;
#pragma unroll
  for (int s = 0; s < 8; ++s) seg += (g >= a.end[s]) ? 1 : 0;
  long base = (seg == 0) ? 0 : a.end[seg - 1];
  long off = g - base + (long)threadIdx.x * 4;
  const float* src = a.src[seg];
  u16* dst = a.dst[seg];
  f32x4 v = *(const f32x4*)&src[off];
  u16x4 o = { f2b(v[0]), f2b(v[1]), f2b(v[2]), f2b(v[3]) };
  *(u16x4*)&dst[off] = o;
}

// ---------------------------------------------------------------------------
// C[m,n] = A[m,:] . B[n,:] + bias[n]  (optional relu), bf16 in/out, f32 acc.
// A: [M,K] bf16 row-major, B: [N,K] bf16 row-major (i.e. B^T of math B).
// 128x128 tile, BK=64, 256 threads = 4 waves in 2x2, each wave 64x64 (4x4 MFMA).
// LDS layout XOR-swizzled: chunk(row, logcol) stored at physcol = logcol^(row&7)
// (swizzle applied on the GLOBAL address side so LDS side stays linear, as
// global_load_lds requires). Row stride 128B -> swizzle spreads quads over all
// 32 banks.
// Block remap: all gridDim.x blocks of one A-stripe get flat ids == same mod 8
// -> same XCD (dispatch heuristic), A-stripe fetched ~once from HBM.
// Requires gridDim.y % 8 == 0.
// ---------------------------------------------------------------------------
#define BM 128
#define BN 128
#define BK 64

__global__ __launch_bounds__(256) void gemm_bt(
    const u16* __restrict__ A, const u16* __restrict__ B,
    const float* __restrict__ bias, u16* __restrict__ C,
    int M, int N, int K, int relu)
{
  __shared__ __attribute__((aligned(16))) u16 As[BM * BK];  // 16 KB
  __shared__ __attribute__((aligned(16))) u16 Bs[BN * BK];  // 16 KB

  const int tid  = threadIdx.x;
  const int lane = tid & 63;
  const int wave = tid >> 6;
  const int lr   = lane & 15;   // M/N index within 16-tile
  const int quad = lane >> 4;   // k: within 32-chunk, k = quad*8 + j
  const int wm = (wave >> 1) * 64;
  const int wn = (wave & 1) * 64;

  // XCD-aware remap (x fastest in HW dispatch order)
  const int Nb = gridDim.x;
  const int flat = blockIdx.y * Nb + blockIdx.x;
  const int sg  = flat / (8 * Nb);
  const int rem = flat - sg * 8 * Nb;
  const int bx  = rem >> 3;
  const int by  = sg * 8 + (rem & 7);

  const long m0 = (long)by * BM;
  const long n0 = (long)bx * BN;

  // staging: 1024 chunks of 16B per matrix; thread t does chunks t+{0,256,512,768}
  // LDS chunk p (linear): row = p>>3, physcol = p&7, logcol = physcol ^ (row&7)
  long goff[4];
#pragma unroll
  for (int c = 0; c < 4; ++c) {
    const int p = tid + 256 * c;
    const int row = p >> 3;
    const int logcol = (p & 7) ^ (row & 7);
    goff[c] = (long)row * K + logcol * 8;
  }

  const u16* Ab = A + m0 * K;
  const u16* Bb = B + n0 * K;

  // fragment LDS addresses: row = wm/wn + i*16 + lr; row&7 == lr&7,
  // so phys col chunk = (quad + kh*4) ^ (lr&7), row-independent.
  const int ph0 = quad ^ (lane & 7);        // kh=0
  const int ph1 = (quad + 4) ^ (lane & 7);  // kh=1

  f32x4 acc[4][4] = {};

  for (int k0 = 0; k0 < K; k0 += BK) {
    __syncthreads();
#pragma unroll
    for (int c = 0; c < 4; ++c) {
      gl2lds16(Ab + goff[c] + k0, &As[(tid + 256 * c) * 8]);
      gl2lds16(Bb + goff[c] + k0, &Bs[(tid + 256 * c) * 8]);
    }
    __syncthreads();

#pragma unroll
    for (int kh = 0; kh < 2; ++kh) {
      const int ph = kh ? ph1 : ph0;
      bf16x8 af[4], bff[4];
#pragma unroll
      for (int i = 0; i < 4; ++i)
        af[i] = *(const bf16x8*)&As[(wm + i * 16 + lr) * BK + ph * 8];
#pragma unroll
      for (int i = 0; i < 4; ++i)
        bff[i] = *(const bf16x8*)&Bs[(wn + i * 16 + lr) * BK + ph * 8];
#pragma unroll
      for (int i = 0; i < 4; ++i)
#pragma unroll
        for (int j = 0; j < 4; ++j)
          acc[i][j] = __builtin_amdgcn_mfma_f32_16x16x32_bf16(af[i], bff[j], acc[i][j], 0, 0, 0);
    }
  }

  // C/D layout: col = lane&15, row = quad*4 + reg
#pragma unroll
  for (int j = 0; j < 4; ++j) {
    const int col = wn + j * 16 + lr;
    const float bv = bias[n0 + col];
#pragma unroll
    for (int i = 0; i < 4; ++i) {
#pragma unroll
      for (int r = 0; r < 4; ++r) {
        const int row = wm + i * 16 + quad * 4 + r;
        float v = acc[i][j][r] + bv;
        if (relu) v = fmaxf(v, 0.0f);
        C[(m0 + row) * (long)N + (n0 + col)] = f2b(v);
      }
    }
  }
}

// ---------------------------------------------------------------------------
// Attention per (b,a): 1024 blocks, 256 threads.
//  q tile: Qp contiguous [h=256][l=128] at row 32a
//  k/v pre: Kp/Vp contiguous [h=256][kk=64] at row 16a
//  k[h][r] = sum_kk kpre[h][kk]*fac[a][kk][r] (k scaled by 1/16)
//  scores[l][r] = sum_h q[h][l]*k[h][r]; softmax over r (16);
//  ctx[l][h] = sum_r attn[l][r]*v[h][r], written contiguous [l][h]
// ---------------------------------------------------------------------------
__global__ __launch_bounds__(256) void attn_kernel(
    const u16* __restrict__ Qp, const u16* __restrict__ Kp,
    const u16* __restrict__ Vp, const float* __restrict__ factor,
    u16* __restrict__ Ctx)
{
  __shared__ __attribute__((aligned(16))) float fac_s[64 * 16];
  __shared__ __attribute__((aligned(16))) float k_s[256][20];
  __shared__ __attribute__((aligned(16))) float v_s[256][20];
  __shared__ __attribute__((aligned(16))) float s_s[128][20];

  const int t = threadIdx.x;
  const int b = blockIdx.x >> 6;
  const int a = blockIdx.x & 63;

  for (int i = t; i < 1024; i += 256) fac_s[i] = factor[a * 1024 + i];
  __syncthreads();

  // phase 1: k_s / v_s, thread t <-> h = t
  {
    const long kb = (((long)(b * 1024 + a * 16)) << 10) + (long)t * 64;
    float kacc[16] = {}, vacc[16] = {};
    for (int kk8 = 0; kk8 < 64; kk8 += 8) {
      u16x8 kv8 = *(const u16x8*)&Kp[kb + kk8];
      u16x8 vv8 = *(const u16x8*)&Vp[kb + kk8];
#pragma unroll
      for (int j = 0; j < 8; ++j) {
        const float kv = b2f(kv8[j]), vv = b2f(vv8[j]);
        const float* fr = &fac_s[(kk8 + j) * 16];
#pragma unroll
        for (int r = 0; r < 16; ++r) { kacc[r] += kv * fr[r]; vacc[r] += vv * fr[r]; }
      }
    }
#pragma unroll
    for (int r = 0; r < 16; ++r) { k_s[t][r] = kacc[r] * 0.0625f; v_s[t][r] = vacc[r]; }
  }
  __syncthreads();

  // phase 2: scores; thread t <-> (l = t&127, half = t>>7 covering 8 r's)
  {
    const int l = t & 127, half = t >> 7;
    const long qb = (((long)(b * 2048 + a * 32)) << 10) + l;
    f32x4 acc0 = {}, acc1 = {};
    for (int h = 0; h < 256; ++h) {
      const float qv = b2f(Qp[qb + (long)h * 128]);
      f32x4 k0 = *(const f32x4*)&k_s[h][half * 8];
      f32x4 k1 = *(const f32x4*)&k_s[h][half * 8 + 4];
      acc0 += k0 * qv;
      acc1 += k1 * qv;
    }
    *(f32x4*)&s_s[l][half * 8]     = acc0;
    *(f32x4*)&s_s[l][half * 8 + 4] = acc1;
  }
  __syncthreads();

  // phase 3: softmax over r, threads 0..127
  if (t < 128) {
    float vals[16];
    float m = -1e30f;
#pragma unroll
    for (int r = 0; r < 16; ++r) { vals[r] = s_s[t][r]; m = fmaxf(m, vals[r]); }
    float sum = 0.0f;
#pragma unroll
    for (int r = 0; r < 16; ++r) { vals[r] = __expf(vals[r] - m); sum += vals[r]; }
    const float inv = 1.0f / sum;
#pragma unroll
    for (int r = 0; r < 16; ++r) s_s[t][r] = vals[r] * inv;
  }
  __syncthreads();

  // phase 4: ctx[l][h], thread t <-> h = t
  {
    f32x4 v0 = *(const f32x4*)&v_s[t][0];
    f32x4 v1 = *(const f32x4*)&v_s[t][4];
    f32x4 v2 = *(const f32x4*)&v_s[t][8];
    f32x4 v3 = *(const f32x4*)&v_s[t][12];
    const long cb = (((long)(b * 2048 + a * 32)) << 10) + t;
    for (int l = 0; l < 128; ++l) {
      f32x4 a0 = *(const f32x4*)&s_s[l][0];
      f32x4 a1 = *(const f32x4*)&s_s[l][4];
      f32x4 a2 = *(const f32x4*)&s_s[l][8];
      f32x4 a3 = *(const f32x4*)&s_s[l][12];
      f32x4 p = a0 * v0 + a1 * v1 + a2 * v2 + a3 * v3;
      Ctx[cb + (long)l * 256] = f2b(p[0] + p[1] + p[2] + p[3]);
    }
  }
}

// ---------------------------------------------------------------------------
// Residual + LayerNorm: one block (256 thr) per row of 1024.
// x = bf16(Y) + Q(f32); out = (x-mu)*rsqrt(var+eps)*gamma + beta
// ---------------------------------------------------------------------------
__global__ __launch_bounds__(256) void ln_kernel(
    const u16* __restrict__ Y, const float* __restrict__ Qin,
    const float* __restrict__ gamma, const float* __restrict__ beta,
    float* __restrict__ out)
{
  const long row = blockIdx.x;
  const int t = threadIdx.x;
  const long base = (row << 10) + (long)t * 4;

  u16x4 y4 = *(const u16x4*)&Y[base];
  f32x4 q4 = *(const f32x4*)&Qin[base];
  f32x4 x;
#pragma unroll
  for (int c = 0; c < 4; ++c) x[c] = b2f(y4[c]) + q4[c];

  float s  = x[0] + x[1] + x[2] + x[3];
  float sq = x[0]*x[0] + x[1]*x[1] + x[2]*x[2] + x[3]*x[3];
#pragma unroll
  for (int o = 1; o < 64; o <<= 1) {
    s  += __shfl_xor(s, o);
    sq += __shfl_xor(sq, o);
  }
  __shared__ float red[8];
  if ((t & 63) == 0) { red[(t >> 6) * 2] = s; red[(t >> 6) * 2 + 1] = sq; }
  __syncthreads();
  s  = red[0] + red[2] + red[4] + red[6];
  sq = red[1] + red[3] + red[5] + red[7];

  const float mean = s * (1.0f / 1024.0f);
  const float var  = sq * (1.0f / 1024.0f) - mean * mean;
  const float rstd = rsqrtf(var + 1e-5f);

  f32x4 g4 = *(const f32x4*)&gamma[t * 4];
  f32x4 be4 = *(const f32x4*)&beta[t * 4];
  f32x4 o4;
#pragma unroll
  for (int c = 0; c < 4; ++c) o4[c] = (x[c] - mean) * rstd * g4[c] + be4[c];
  *(f32x4*)&out[base] = o4;
}

// ---------------------------------------------------------------------------
extern "C" void kernel_launch(void* const* d_in, const int* in_sizes, int n_in,
                              void* d_out, int out_size, void* d_ws, size_t ws_size,
                              hipStream_t stream)
{
  (void)in_sizes; (void)n_in; (void)out_size; (void)ws_size;
  const float* Q      = (const float*)d_in[0];
  const float* K      = (const float*)d_in[1];
  const float* V      = (const float*)d_in[2];
  const float* WQ     = (const float*)d_in[3];
  const float* bQ     = (const float*)d_in[4];
  const float* WK     = (const float*)d_in[5];
  const float* bK     = (const float*)d_in[6];
  const float* WV     = (const float*)d_in[7];
  const float* bV     = (const float*)d_in[8];
  const float* factor = (const float*)d_in[9];
  const float* W1     = (const float*)d_in[10];
  const float* b1     = (const float*)d_in[11];
  const float* W2     = (const float*)d_in[12];
  const float* b2     = (const float*)d_in[13];
  const float* gamma  = (const float*)d_in[14];
  const float* beta   = (const float*)d_in[15];
  float* out = (float*)d_out;

  const long NQ = 33554432L;  // 16*2048*1024
  const long NK = 16777216L;  // 16*1024*1024
  const long ND = 1048576L;   // 1024*1024
  const long NW = 2097152L;   // 2048*1024

  char* w = (char*)d_ws;
  u16* Qb  = (u16*)(w);                    // 64 MB
  u16* Kb  = (u16*)(w + 67108864L);        // 32 MB
  u16* Vb  = (u16*)(w + 100663296L);       // 32 MB
  u16* WQb = (u16*)(w + 134217728L);       // 2 MB
  u16* WKb = (u16*)(w + 136314880L);       // 2 MB
  u16* WVb = (u16*)(w + 138412032L);       // 2 MB
  u16* W1b = (u16*)(w + 140509184L);       // 4 MB
  u16* W2b = (u16*)(w + 144703488L);       // 4 MB
  u16* Qp  = (u16*)(w + 148897792L);       // 64 MB
  u16* Kp  = (u16*)(w + 216006656L);       // 32 MB
  u16* Vp  = (u16*)(w + 249561088L);       // 32 MB
  u16* Ctx = (u16*)(w + 283115520L);       // 64 MB  -> peak ~350 MB
  u16* Hb  = (u16*)(w);                    // reuse Qb/Kb/Vb region (128 MB)
  u16* Yb  = (u16*)(w + 216006656L);       // reuse Kp/Vp region (64 MB)

  // fused f32->bf16 conversions (8 segments, one launch)
  CvtArgs ca;
  ca.src[0] = Q;  ca.dst[0] = Qb;
  ca.src[1] = K;  ca.dst[1] = Kb;
  ca.src[2] = V;  ca.dst[2] = Vb;
  ca.src[3] = WQ; ca.dst[3] = WQb;
  ca.src[4] = WK; ca.dst[4] = WKb;
  ca.src[5] = WV; ca.dst[5] = WVb;
  ca.src[6] = W1; ca.dst[6] = W1b;
  ca.src[7] = W2; ca.dst[7] = W2b;
  long sizes[8] = { NQ, NK, NK, ND, ND, ND, NW, NW };
  long cum = 0;
  for (int i = 0; i < 8; ++i) { cum += sizes[i]; ca.end[i] = cum; }
  cvt_all<<<(int)(cum / 1024), 256, 0, stream>>>(ca);

  // projections
  gemm_bt<<<dim3(8, 256),  256, 0, stream>>>(Qb, WQb, bQ, Qp, 32768, 1024, 1024, 0);
  gemm_bt<<<dim3(8, 128),  256, 0, stream>>>(Kb, WKb, bK, Kp, 16384, 1024, 1024, 0);
  gemm_bt<<<dim3(8, 128),  256, 0, stream>>>(Vb, WVb, bV, Vp, 16384, 1024, 1024, 0);

  // low-rank attention
  attn_kernel<<<1024, 256, 0, stream>>>(Qp, Kp, Vp, factor, Ctx);

  // FFN
  gemm_bt<<<dim3(16, 256), 256, 0, stream>>>(Ctx, W1b, b1, Hb, 32768, 2048, 1024, 1);
  gemm_bt<<<dim3(8, 256),  256, 0, stream>>>(Hb, W2b, b2, Yb, 32768, 1024, 2048, 0);

  // residual + layernorm
  ln_kernel<<<32768, 256, 0, stream>>>(Yb, Q, gamma, beta, out);
}